// Round 4
// baseline (65.183 us; speedup 1.0000x reference)
//
#include <hip/hip_runtime.h>
#include <cstdint>

#define T_STEPS 16
#define V_VECS  1024
#define D_DIM   128
#define B_BATCH 2048
#define BCAP    2048          // per-t list capacity (bulletproof: n <= B)

// ---------------------------------------------------------------------------
// Single fused kernel. Grid (16 vtiles, 16 t, 2 z), block 256 = 16(tv)x16(tb).
//
// Phase 0: stable block-local bucketing — ballot+prefix compaction of
//          {b : idx[b]==t} into LDS blist. Deterministic order => every block
//          for the same t derives the IDENTICAL list (slot indices agree).
// Phase 1: stage A^T (64v x 128k, k-major) once; fused inverse norms.
// Phase 2: chunk loop (cs = z*64; cs += 128): stage X^T for 64 bucketed b's,
//          4x4 register-tile GEMM over k=128, invnorm scale, per-thread
//          argmax over 4 v, shfl_xor butterfly over 16 tv lanes, write local
//          best packed (ordered_score, 1023-v) to partial[(t,bi)][vt].
// Phase 3: threadfence + done-counter. (old&15)==15 fires exactly once per
//          (t,z) regardless of initial counter garbage (16 consecutive
//          increments cover all residues mod 16) => no ws init needed.
//          Last block max-reduces 16 partials per b (ties -> lowest v,
//          matches jnp.argmax) and copies the raw winning vectors to out.
// ---------------------------------------------------------------------------
__global__ __launch_bounds__(256) void k_all(const float* __restrict__ X,
                                             const float* __restrict__ L,
                                             const int* __restrict__ idx,
                                             unsigned long long* __restrict__ partial,
                                             unsigned int* __restrict__ done,
                                             float* __restrict__ out) {
    __shared__ __align__(16) float As[D_DIM][64];   // 32 KB
    __shared__ __align__(16) float Xs[D_DIM][64];   // 32 KB
    __shared__ float npart[4][64];
    __shared__ float invn_s[64];
    __shared__ int   blist[BCAP];                   // 8 KB
    __shared__ int   wcnt[4];
    __shared__ int   vArr[64];
    __shared__ int   bArr[64];
    __shared__ int   lastflag;

    const int t    = blockIdx.y;
    const int vt   = blockIdx.x;
    const int v0   = vt * 64;
    const int z    = blockIdx.z;
    const int tid  = threadIdx.x;
    const int lane = tid & 63;
    const int w    = tid >> 6;

    // ---- phase 0: stable bucketing (identical blist in every block of t) ----
    int nbase = 0;
    for (int r = 0; r < 8; ++r) {
        const int b = r * 256 + tid;
        const bool m = (idx[b] == t);
        const unsigned long long bal = __ballot(m);
        const int wpre = __popcll(bal & ((1ull << lane) - 1ull));
        if (lane == 0) wcnt[w] = __popcll(bal);
        __syncthreads();
        const int c0 = wcnt[0], c1 = wcnt[1], c2 = wcnt[2], c3 = wcnt[3];
        int base = nbase;
        if (w > 0) base += c0;
        if (w > 1) base += c1;
        if (w > 2) base += c2;
        if (m) blist[base + wpre] = b;
        nbase += c0 + c1 + c2 + c3;
        __syncthreads();
    }
    const int n = nbase;
    if (z * 64 >= n) return;             // uniform: same n in all blocks of t

    // ---- phase 1: stage A^T once (k-major) + fused norms ----
    const float4* LA = (const float4*)(L + (size_t)(t * V_VECS + v0) * D_DIM);
    float ss = 0.f;
    #pragma unroll
    for (int p = 0; p < 8; ++p) {
        const int k4 = w + 4 * p;              // 0..31
        const float4 g = LA[lane * 32 + k4];
        As[4 * k4 + 0][lane] = g.x;
        As[4 * k4 + 1][lane] = g.y;
        As[4 * k4 + 2][lane] = g.z;
        As[4 * k4 + 3][lane] = g.w;
        ss += g.x * g.x + g.y * g.y + g.z * g.z + g.w * g.w;
    }
    npart[w][lane] = ss;
    __syncthreads();
    if (tid < 64) {
        const float s = npart[0][tid] + npart[1][tid] + npart[2][tid] + npart[3][tid];
        invn_s[tid] = rsqrtf(fmaxf(s, 1e-12f));
    }
    // invn_s visible to all after the barrier inside the chunk loop.

    const int tv = tid & 15;     // v-group: v = v0 + tv*4 + i
    const int tb = tid >> 4;     // b-group: b-slot = cs + tb*4 + j
    const float4* XA = (const float4*)X;

    // ---- phase 2: chunk loop ----
    for (int cs = z * 64; cs < n; cs += 128) {
        __syncthreads();         // prior Xs reads + npart/invn writes settled

        const int brow = cs + lane;
        const int bg = (brow < n) ? blist[brow] : -1;
        #pragma unroll
        for (int p = 0; p < 8; ++p) {
            const int k4 = w + 4 * p;
            float4 g = make_float4(0.f, 0.f, 0.f, 0.f);
            if (bg >= 0) g = XA[bg * 32 + k4];
            Xs[4 * k4 + 0][lane] = g.x;
            Xs[4 * k4 + 1][lane] = g.y;
            Xs[4 * k4 + 2][lane] = g.z;
            Xs[4 * k4 + 3][lane] = g.w;
        }
        __syncthreads();

        float acc[4][4] = {};
        #pragma unroll 16
        for (int k = 0; k < D_DIM; ++k) {
            const float4 av = *(const float4*)&As[k][tv * 4];
            const float4 xb = *(const float4*)&Xs[k][tb * 4];
            const float a[4] = {av.x, av.y, av.z, av.w};
            const float x[4] = {xb.x, xb.y, xb.z, xb.w};
            #pragma unroll
            for (int i = 0; i < 4; ++i)
                #pragma unroll
                for (int j = 0; j < 4; ++j)
                    acc[i][j] += a[i] * x[j];
        }

        const float invp[4] = {invn_s[tv * 4 + 0], invn_s[tv * 4 + 1],
                               invn_s[tv * 4 + 2], invn_s[tv * 4 + 3]};

        #pragma unroll
        for (int j = 0; j < 4; ++j) {
            float s = acc[0][j] * invp[0];
            int   c = v0 + tv * 4;
            #pragma unroll
            for (int i = 1; i < 4; ++i) {
                const float si = acc[i][j] * invp[i];
                const int   ci = v0 + tv * 4 + i;
                if (si > s) { s = si; c = ci; }      // strict: lowest v wins tie
            }
            #pragma unroll
            for (int m = 8; m >= 1; m >>= 1) {       // reduce across tv lanes
                const float u  = __shfl_xor(s, m);
                const int   cu = __shfl_xor(c, m);
                if (u > s || (u == s && cu < c)) { s = u; c = cu; }
            }
            if (tv == 0) {
                const int bi = cs + tb * 4 + j;
                if (bi < n) {
                    unsigned int ub = __float_as_uint(s);
                    ub = (ub & 0x80000000u) ? ~ub : (ub | 0x80000000u);
                    partial[((size_t)(t * BCAP + bi) << 4) + vt] =
                        ((unsigned long long)ub << 32) |
                        (unsigned long long)(unsigned)(1023 - c);
                }
            }
        }
    }

    // ---- phase 3: completion + fused gather ----
    __threadfence();
    __syncthreads();
    if (tid == 0) {
        const unsigned int old = atomicAdd(&done[t * 2 + z], 1u);
        lastflag = ((old & 15u) == 15u) ? 1 : 0;
    }
    __syncthreads();
    if (!lastflag) return;
    __threadfence();

    const int l32 = tid & 31;
    for (int cs = z * 64; cs < n; cs += 128) {
        const int nb = min(64, n - cs);
        if (tid < nb) {
            const int bi = cs + tid;
            const unsigned long long* pp = &partial[(size_t)(t * BCAP + bi) << 4];
            unsigned long long best = pp[0];
            #pragma unroll
            for (int q = 1; q < 16; ++q) {
                const unsigned long long k2 = pp[q];
                if (k2 > best) best = k2;
            }
            vArr[tid] = 1023 - (int)(best & 0xffffffffull);
            bArr[tid] = blist[bi];
        }
        __syncthreads();
        for (int q = tid >> 5; q < nb; q += 8) {
            const int b = bArr[q], v = vArr[q];
            ((float4*)out)[b * 32 + l32] =
                ((const float4*)L)[(size_t)(t * V_VECS + v) * 32 + l32];
        }
        __syncthreads();
    }
}

extern "C" void kernel_launch(void* const* d_in, const int* in_sizes, int n_in,
                              void* d_out, int out_size, void* d_ws, size_t ws_size,
                              hipStream_t stream) {
    const float* X  = (const float*)d_in[0];   // (B, D, 1) f32
    const float* L  = (const float*)d_in[1];   // (T, V, D) f32
    const int* idx  = (const int*)d_in[2];     // (B,) int
    float* out      = (float*)d_out;           // (B, D) f32

    char* ws = (char*)d_ws;
    unsigned int* done        = (unsigned int*)ws;                     // 128 B
    unsigned long long* part  = (unsigned long long*)(ws + 4096);      // 4 MiB

    hipLaunchKernelGGL(k_all, dim3(16, 16, 2), dim3(256), 0, stream,
                       X, L, idx, part, done, out);
}

// Round 7
// 28.337 us; speedup vs baseline: 2.3003x; 2.3003x over previous
//
#include <hip/hip_runtime.h>
#include <cstdint>

#define T_STEPS 16
#define V_VECS  1024
#define D_DIM   128
#define B_BATCH 2048
#define BCAP    2048          // per-t list capacity (bulletproof: n <= B)

// ---------------------------------------------------------------------------
// k_score: grid (16 vtiles, 16 t, 2 z), block 256 = 16(tv) x 16(tb).
//
// Phase 0: stable block-local bucketing — ballot+prefix compaction of
//          {b : idx[b]==t} into LDS blist. Deterministic => every block of t
//          derives the IDENTICAL list. (Kills the serialized bucket kernel.)
// Phase 1: stage A^T (64v x 128k, k-major) once; fused inverse norms.
// Phase 2: chunk loop (cs = z*64; cs += 128): stage X^T for 64 bucketed b's,
//          4x4 register-tile GEMM over k=128, invnorm scale, per-thread
//          argmax over 4 v, shfl_xor butterfly over 16 tv lanes, then a
//          PLAIN STORE of the packed (ordered_score:32 | (1023-v):16 | b:16)
//          key to partial[vt][t][bi]. No atomics, no ws init needed: gather
//          reads only slots written this launch. Cross-block visibility is
//          provided by the KERNEL BOUNDARY (the only mechanism that has
//          passed on this chip; intra-kernel protocols failed rounds 4-6).
// ---------------------------------------------------------------------------
__global__ __launch_bounds__(256) void k_score(const float* __restrict__ X,
                                               const float* __restrict__ L,
                                               const int* __restrict__ idx,
                                               unsigned long long* __restrict__ partial,
                                               int* __restrict__ counts) {
    __shared__ __align__(16) float As[D_DIM][64];   // 32 KB
    __shared__ __align__(16) float Xs[D_DIM][64];   // 32 KB
    __shared__ float npart[4][64];
    __shared__ float invn_s[64];
    __shared__ int   blist[BCAP];                   // 8 KB
    __shared__ int   wcnt[4];

    const int t    = blockIdx.y;
    const int vt   = blockIdx.x;
    const int v0   = vt * 64;
    const int z    = blockIdx.z;
    const int tid  = threadIdx.x;
    const int lane = tid & 63;
    const int w    = tid >> 6;

    // ---- phase 0: stable bucketing (identical blist in every block of t) ----
    int nbase = 0;
    for (int r = 0; r < 8; ++r) {
        const int b = r * 256 + tid;
        const bool m = (idx[b] == t);
        const unsigned long long bal = __ballot(m);
        const int wpre = __popcll(bal & ((1ull << lane) - 1ull));
        if (lane == 0) wcnt[w] = __popcll(bal);
        __syncthreads();
        const int c0 = wcnt[0], c1 = wcnt[1], c2 = wcnt[2], c3 = wcnt[3];
        int base = nbase;
        if (w > 0) base += c0;
        if (w > 1) base += c1;
        if (w > 2) base += c2;
        if (m) blist[base + wpre] = b;
        nbase += c0 + c1 + c2 + c3;
        __syncthreads();
    }
    const int n = nbase;
    if (vt == 0 && z == 0 && tid == 0) counts[t] = n;   // before early return
    if (z * 64 >= n) return;             // uniform: same n in all blocks of t

    // ---- phase 1: stage A^T once (k-major) + fused norms ----
    const float4* LA = (const float4*)(L + (size_t)(t * V_VECS + v0) * D_DIM);
    float ss = 0.f;
    #pragma unroll
    for (int p = 0; p < 8; ++p) {
        const int k4 = w + 4 * p;              // 0..31
        const float4 g = LA[lane * 32 + k4];
        As[4 * k4 + 0][lane] = g.x;
        As[4 * k4 + 1][lane] = g.y;
        As[4 * k4 + 2][lane] = g.z;
        As[4 * k4 + 3][lane] = g.w;
        ss += g.x * g.x + g.y * g.y + g.z * g.z + g.w * g.w;
    }
    npart[w][lane] = ss;
    __syncthreads();
    if (tid < 64) {
        const float s = npart[0][tid] + npart[1][tid] + npart[2][tid] + npart[3][tid];
        invn_s[tid] = rsqrtf(fmaxf(s, 1e-12f));
    }
    // invn_s visible to all after the barrier inside the chunk loop.

    const int tv = tid & 15;     // v-group: v = v0 + tv*4 + i
    const int tb = tid >> 4;     // b-group: b-slot = cs + tb*4 + j
    const float4* XA = (const float4*)X;

    // ---- phase 2: chunk loop ----
    for (int cs = z * 64; cs < n; cs += 128) {
        __syncthreads();         // prior Xs reads + npart/invn writes settled

        const int brow = cs + lane;
        const int bg = (brow < n) ? blist[brow] : -1;
        #pragma unroll
        for (int p = 0; p < 8; ++p) {
            const int k4 = w + 4 * p;
            float4 g = make_float4(0.f, 0.f, 0.f, 0.f);
            if (bg >= 0) g = XA[bg * 32 + k4];
            Xs[4 * k4 + 0][lane] = g.x;
            Xs[4 * k4 + 1][lane] = g.y;
            Xs[4 * k4 + 2][lane] = g.z;
            Xs[4 * k4 + 3][lane] = g.w;
        }
        __syncthreads();

        float acc[4][4] = {};
        #pragma unroll 16
        for (int k = 0; k < D_DIM; ++k) {
            const float4 av = *(const float4*)&As[k][tv * 4];
            const float4 xb = *(const float4*)&Xs[k][tb * 4];
            const float a[4] = {av.x, av.y, av.z, av.w};
            const float x[4] = {xb.x, xb.y, xb.z, xb.w};
            #pragma unroll
            for (int i = 0; i < 4; ++i)
                #pragma unroll
                for (int j = 0; j < 4; ++j)
                    acc[i][j] += a[i] * x[j];
        }

        const float invp[4] = {invn_s[tv * 4 + 0], invn_s[tv * 4 + 1],
                               invn_s[tv * 4 + 2], invn_s[tv * 4 + 3]};

        #pragma unroll
        for (int j = 0; j < 4; ++j) {
            float s = acc[0][j] * invp[0];
            int   c = v0 + tv * 4;
            #pragma unroll
            for (int i = 1; i < 4; ++i) {
                const float si = acc[i][j] * invp[i];
                const int   ci = v0 + tv * 4 + i;
                if (si > s) { s = si; c = ci; }      // strict: lowest v wins tie
            }
            #pragma unroll
            for (int m = 8; m >= 1; m >>= 1) {       // reduce across tv lanes
                const float u  = __shfl_xor(s, m);
                const int   cu = __shfl_xor(c, m);
                if (u > s || (u == s && cu < c)) { s = u; c = cu; }
            }
            if (tv == 0) {
                const int bi = cs + tb * 4 + j;
                if (bi < n) {
                    unsigned int ub = __float_as_uint(s);
                    ub = (ub & 0x80000000u) ? ~ub : (ub | 0x80000000u);
                    const unsigned long long key =
                        ((unsigned long long)ub << 32) |
                        ((unsigned long long)(unsigned)(1023 - c) << 16) |
                        (unsigned long long)(unsigned)blist[bi];
                    partial[((size_t)vt * T_STEPS + t) * BCAP + bi] = key;
                }
            }
        }
    }
}

// ---------------------------------------------------------------------------
// k_gather: grid (32 bi-chunks, 16 t), block 256. Reads counts/partial across
// the kernel boundary (full visibility). Per valid bi: max-reduce the 16
// vt-keys (higher score wins; tie -> higher (1023-v) -> lower v, matching
// jnp.argmax), decode (b, v), copy the raw winning vector (bit-exact).
// ---------------------------------------------------------------------------
__global__ __launch_bounds__(256) void k_gather(const float* __restrict__ L,
                                                const int* __restrict__ counts,
                                                const unsigned long long* __restrict__ partial,
                                                float* __restrict__ out) {
    __shared__ int vArr[64];
    __shared__ int bArr[64];

    const int t  = blockIdx.y;
    const int cs = blockIdx.x * 64;
    const int n  = counts[t];
    if (cs >= n) return;

    const int tid = threadIdx.x;
    const int nb  = min(64, n - cs);
    if (tid < nb) {
        const int bi = cs + tid;
        unsigned long long best = partial[(size_t)t * BCAP + bi];   // vt=0
        #pragma unroll
        for (int q = 1; q < 16; ++q) {
            const unsigned long long k2 =
                partial[((size_t)q * T_STEPS + t) * BCAP + bi];
            if (k2 > best) best = k2;
        }
        vArr[tid] = 1023 - (int)((best >> 16) & 0xffffull);
        bArr[tid] = (int)(best & 0xffffull);
    }
    __syncthreads();

    const int l32 = tid & 31;
    for (int q = tid >> 5; q < nb; q += 8) {
        const int b = bArr[q], v = vArr[q];
        ((float4*)out)[b * 32 + l32] =
            ((const float4*)L)[(size_t)(t * V_VECS + v) * 32 + l32];
    }
}

extern "C" void kernel_launch(void* const* d_in, const int* in_sizes, int n_in,
                              void* d_out, int out_size, void* d_ws, size_t ws_size,
                              hipStream_t stream) {
    const float* X  = (const float*)d_in[0];   // (B, D, 1) f32
    const float* L  = (const float*)d_in[1];   // (T, V, D) f32
    const int* idx  = (const int*)d_in[2];     // (B,) int
    float* out      = (float*)d_out;           // (B, D) f32

    char* ws = (char*)d_ws;
    int* counts               = (int*)ws;                              // 64 B
    unsigned long long* part  = (unsigned long long*)(ws + 4096);      // 4 MiB

    hipLaunchKernelGGL(k_score,  dim3(16, 16, 2), dim3(256), 0, stream,
                       X, L, idx, part, counts);
    hipLaunchKernelGGL(k_gather, dim3(32, 16),    dim3(256), 0, stream,
                       L, counts, part, out);
}